// Round 16
// baseline (100.286 us; speedup 1.0000x reference)
//
#include <hip/hip_runtime.h>

#define HIDDEN 4096
#define RANK   256
#define G      16
#define NTH    1024   // 16 waves, 1 block/CU (LDS-forced)
#define TB     4      // tokens per wave, processed as 2 chunks of 2

typedef _Float16 h2d __attribute__((ext_vector_type(2)));
typedef float    f4v __attribute__((ext_vector_type(4)));

__device__ __forceinline__ unsigned int pkf16(float a, float b) {
    auto h = __builtin_amdgcn_cvt_pkrtz(a, b);
    return __builtin_bit_cast(unsigned int, h);
}
__device__ __forceinline__ float dot2(unsigned int a, unsigned int b, float c) {
    return __builtin_amdgcn_fdot2(__builtin_bit_cast(h2d, a),
                                  __builtin_bit_cast(h2d, b), c, false);
}
__device__ __forceinline__ float4 f4add(float4 a, float4 b) {
    return make_float4(a.x + b.x, a.y + b.y, a.z + b.z, a.w + b.w);
}

// ---------------------------------------------------------------------------
// pack: Mp[pr*256 + k] = {f16 M[2pr][k], f16 M[2pr+1][k]}   (128 KB, once)
// ---------------------------------------------------------------------------
__global__ __launch_bounds__(256)
void mora_pack(const float* __restrict__ Mg, unsigned int* __restrict__ Mp) {
    const int idx = blockIdx.x * 256 + threadIdx.x;    // 0..32767
    const int pr  = idx >> 8;
    const int k   = idx & 255;
    Mp[idx] = pkf16(Mg[(size_t)(2 * pr) * RANK + k],
                    Mg[(size_t)(2 * pr + 1) * RANK + k]);
}

// ---------------------------------------------------------------------------
// fused, stream-mixing. Barrier ONLY after M staging; each wave then runs
// [compress 2 tok][expand][store 2 tok][compress next 2 tok]... — stores
// have no consumers, so the next chunk's reads issue immediately after
// them: read and write HBM streams overlap within every wave, and 16
// drifting waves/CU keep both directions active continuously.
// Dynamic LDS: [0,131072) M f16-pairs; [131072,147456) ostage f32[16][256].
// ---------------------------------------------------------------------------
__global__ __launch_bounds__(NTH)
void mora_fused(const float* __restrict__ x,          // [T, HIDDEN]
                const unsigned int* __restrict__ Mp,  // [128][256] f16 pairs
                float* __restrict__ out)              // [T, HIDDEN]
{
    extern __shared__ unsigned char smem[];
    unsigned int* Ml = (unsigned int*)smem;            // [128][256]
    float* ostage    = (float*)(smem + 131072);        // [16][256]

    const int  tid  = threadIdx.x;
    const int  w    = tid >> 6;    // wave 0..15
    const int  l    = tid & 63;
    const long tok0 = (long)blockIdx.x * 64 + (long)w * TB;

    // ---- stage full packed M -> LDS (8192 uint4, coalesced, linear) ----
    {
        const uint4* src = (const uint4*)Mp;
        uint4* dst = (uint4*)Ml;
        #pragma unroll
        for (int i = 0; i < 8; ++i)
            dst[tid + (i << 10)] = src[tid + (i << 10)];
    }
    __syncthreads();   // drains only M staging (cheap: 128 KB from L2)

    const uint4* Ml4 = (const uint4*)Ml + l;   // pair-row stride = 64 uint4
    float* ost = ostage + w * RANK;            // per-wave private

    #pragma unroll
    for (int c = 0; c < TB / 2; ++c) {
        // ---- compress 2 tokens (lane owns rows 4l..4l+3 = pairs 2l,2l+1)
        unsigned int cp0[2], cp1[2];
        #pragma unroll
        for (int tt = 0; tt < 2; ++tt) {
            const float4* xr =
                (const float4*)(x + (tok0 + 2 * c + tt) * HIDDEN) + l;
            float4 e = xr[0];
            float4 o = xr[64];
            #pragma unroll
            for (int gi = 1; gi < G / 2; ++gi) {
                e = f4add(e, xr[(2 * gi) * 64]);
                o = f4add(o, xr[(2 * gi + 1) * 64]);
            }
            e = f4add(e, o);
            cp0[tt] = pkf16(e.x, e.y);
            cp1[tt] = pkf16(e.z, e.w);
        }

        // ---- expand both tokens with ONE shared M sweep from LDS ----
        float acc[2][4];
        #pragma unroll
        for (int tt = 0; tt < 2; ++tt) {
            acc[tt][0] = 0.f; acc[tt][1] = 0.f;
            acc[tt][2] = 0.f; acc[tt][3] = 0.f;
        }

        #pragma unroll 4
        for (int i = 0; i < 32; ++i) {
            const uint4 m0 = Ml4[(4 * i + 0) << 6];   // 1 KiB b128, no conflict
            const uint4 m1 = Ml4[(4 * i + 1) << 6];
            const uint4 m2 = Ml4[(4 * i + 2) << 6];
            const uint4 m3 = Ml4[(4 * i + 3) << 6];
            #pragma unroll
            for (int tt = 0; tt < 2; ++tt) {
                const unsigned s0 = (unsigned)__builtin_amdgcn_readlane((int)cp0[tt], 2 * i);
                const unsigned s1 = (unsigned)__builtin_amdgcn_readlane((int)cp1[tt], 2 * i);
                const unsigned s2 = (unsigned)__builtin_amdgcn_readlane((int)cp0[tt], 2 * i + 1);
                const unsigned s3 = (unsigned)__builtin_amdgcn_readlane((int)cp1[tt], 2 * i + 1);
                acc[tt][0] = dot2(s0, m0.x, acc[tt][0]);
                acc[tt][1] = dot2(s0, m0.y, acc[tt][1]);
                acc[tt][2] = dot2(s0, m0.z, acc[tt][2]);
                acc[tt][3] = dot2(s0, m0.w, acc[tt][3]);
                acc[tt][0] = dot2(s1, m1.x, acc[tt][0]);
                acc[tt][1] = dot2(s1, m1.y, acc[tt][1]);
                acc[tt][2] = dot2(s1, m1.z, acc[tt][2]);
                acc[tt][3] = dot2(s1, m1.w, acc[tt][3]);
                acc[tt][0] = dot2(s2, m2.x, acc[tt][0]);
                acc[tt][1] = dot2(s2, m2.y, acc[tt][1]);
                acc[tt][2] = dot2(s2, m2.z, acc[tt][2]);
                acc[tt][3] = dot2(s2, m2.w, acc[tt][3]);
                acc[tt][0] = dot2(s3, m3.x, acc[tt][0]);
                acc[tt][1] = dot2(s3, m3.y, acc[tt][1]);
                acc[tt][2] = dot2(s3, m3.z, acc[tt][2]);
                acc[tt][3] = dot2(s3, m3.w, acc[tt][3]);
            }
        }

        // ---- per-wave restage + NT coalesced splat stores ----
        #pragma unroll
        for (int tt = 0; tt < 2; ++tt) {
            ((float4*)ost)[l] =
                make_float4(acc[tt][0], acc[tt][1], acc[tt][2], acc[tt][3]);
            f4v* orow = (f4v*)(out + (tok0 + 2 * c + tt) * HIDDEN);
            #pragma unroll
            for (int sj = 0; sj < 16; ++sj) {
                const float v = ost[(sj << 4) + (l >> 2)];  // 4-lane bcast, free
                const f4v sp = {v, v, v, v};
                __builtin_nontemporal_store(sp, orow + (sj << 6) + l);
            }
        }
    }
}

extern "C" void kernel_launch(void* const* d_in, const int* in_sizes, int n_in,
                              void* d_out, int out_size, void* d_ws, size_t ws_size,
                              hipStream_t stream) {
    const float* x = (const float*)d_in[0];
    const float* M = (const float*)d_in[1];
    float* out     = (float*)d_out;

    unsigned int* Mp = (unsigned int*)d_ws;    // 128 KiB packed M

    const int T = in_sizes[0] / HIDDEN;        // 16384 tokens
    const int smem_bytes = 147456;             // 128 KiB M + 16 KiB ostage

    (void)hipFuncSetAttribute((const void*)mora_fused,
                              hipFuncAttributeMaxDynamicSharedMemorySize,
                              smem_bytes);

    hipLaunchKernelGGL(mora_pack, dim3(128), dim3(256), 0, stream, M, Mp);
    hipLaunchKernelGGL(mora_fused, dim3(T / 64), dim3(NTH), smem_bytes,
                       stream, x, Mp, out);
}

// Round 17
// 90.164 us; speedup vs baseline: 1.1123x; 1.1123x over previous
//
#include <hip/hip_runtime.h>

#define HIDDEN 4096
#define RANK   256
#define G      16
#define NTH    1024   // 16 waves, 1 block/CU (LDS-forced)
#define TB     4      // tokens per wave (16 waves * 4 = 64 tokens/block)

typedef _Float16 h2d __attribute__((ext_vector_type(2)));
typedef float    f4v __attribute__((ext_vector_type(4)));

__device__ __forceinline__ unsigned int pkf16(float a, float b) {
    auto h = __builtin_amdgcn_cvt_pkrtz(a, b);
    return __builtin_bit_cast(unsigned int, h);
}
__device__ __forceinline__ float dot2(unsigned int a, unsigned int b, float c) {
    return __builtin_amdgcn_fdot2(__builtin_bit_cast(h2d, a),
                                  __builtin_bit_cast(h2d, b), c, false);
}
__device__ __forceinline__ float4 f4add(float4 a, float4 b) {
    return make_float4(a.x + b.x, a.y + b.y, a.z + b.z, a.w + b.w);
}

// ---------------------------------------------------------------------------
// pack: Mp[pr*256 + k] = {f16 M[2pr][k], f16 M[2pr+1][k]}   (128 KB, once)
// ---------------------------------------------------------------------------
__global__ __launch_bounds__(256)
void mora_pack(const float* __restrict__ Mg, unsigned int* __restrict__ Mp) {
    const int idx = blockIdx.x * 256 + threadIdx.x;    // 0..32767
    const int pr  = idx >> 8;
    const int k   = idx & 255;
    Mp[idx] = pkf16(Mg[(size_t)(2 * pr) * RANK + k],
                    Mg[(size_t)(2 * pr + 1) * RANK + k]);
}

// ---------------------------------------------------------------------------
// fused == R14 with ONE change: the barrier sits immediately after M staging
// (cheap L2 drain) instead of after compress. Waves then run their whole
// read(64KB) -> compute -> store(64KB) pipeline unsynchronized, so the 16
// waves/CU drift and mix HBM read/write directions continuously instead of
// the CU-wide read-phase -> write-phase R14 enforced.
// Dynamic LDS: [0,131072) M f16-pairs; [131072,147456) ostage f32[16][256].
// ---------------------------------------------------------------------------
__global__ __launch_bounds__(NTH)
void mora_fused(const float* __restrict__ x,          // [T, HIDDEN]
                const unsigned int* __restrict__ Mp,  // [128][256] f16 pairs
                float* __restrict__ out)              // [T, HIDDEN]
{
    extern __shared__ unsigned char smem[];
    unsigned int* Ml = (unsigned int*)smem;            // [128][256]
    float* ostage    = (float*)(smem + 131072);        // [16][256]

    const int  tid  = threadIdx.x;
    const int  w    = tid >> 6;    // wave 0..15
    const int  l    = tid & 63;
    const long tok0 = (long)blockIdx.x * (16 * TB) + (long)w * TB;

    // ---- stage full packed M -> LDS (8192 uint4, coalesced, linear) ----
    {
        const uint4* src = (const uint4*)Mp;
        uint4* dst = (uint4*)Ml;
        #pragma unroll
        for (int i = 0; i < 8; ++i)
            dst[tid + (i << 10)] = src[tid + (i << 10)];
    }
    __syncthreads();   // drains only M staging (128 KB from L2 — cheap)

    // ---- compress (registers only): lane owns rows 4l..4l+3 ----
    unsigned int cp0[TB], cp1[TB];
    #pragma unroll
    for (int t = 0; t < TB; ++t) {
        const float4* xr = (const float4*)(x + (tok0 + t) * HIDDEN) + l;
        float4 e = xr[0];
        float4 o = xr[64];
        #pragma unroll
        for (int gi = 1; gi < G / 2; ++gi) {
            e = f4add(e, xr[(2 * gi) * 64]);
            o = f4add(o, xr[(2 * gi + 1) * 64]);
        }
        e = f4add(e, o);
        cp0[t] = pkf16(e.x, e.y);
        cp1[t] = pkf16(e.z, e.w);
    }

    // ---- expand: acc[t][c] = sum_r comp[t][r] * M[r][4l+c] ----
    float acc[TB][4];
    #pragma unroll
    for (int t = 0; t < TB; ++t) {
        acc[t][0] = 0.f; acc[t][1] = 0.f; acc[t][2] = 0.f; acc[t][3] = 0.f;
    }

    const uint4* Ml4 = (const uint4*)Ml + l;   // pair-row stride = 64 uint4
    #pragma unroll 2
    for (int i = 0; i < 32; ++i) {
        const uint4 m0 = Ml4[(4 * i + 0) << 6];   // 1 KiB b128, conflict-free
        const uint4 m1 = Ml4[(4 * i + 1) << 6];
        const uint4 m2 = Ml4[(4 * i + 2) << 6];
        const uint4 m3 = Ml4[(4 * i + 3) << 6];
        #pragma unroll
        for (int t = 0; t < TB; ++t) {
            const unsigned s0 = (unsigned)__builtin_amdgcn_readlane((int)cp0[t], 2 * i);
            const unsigned s1 = (unsigned)__builtin_amdgcn_readlane((int)cp1[t], 2 * i);
            const unsigned s2 = (unsigned)__builtin_amdgcn_readlane((int)cp0[t], 2 * i + 1);
            const unsigned s3 = (unsigned)__builtin_amdgcn_readlane((int)cp1[t], 2 * i + 1);
            acc[t][0] = dot2(s0, m0.x, acc[t][0]);
            acc[t][1] = dot2(s0, m0.y, acc[t][1]);
            acc[t][2] = dot2(s0, m0.z, acc[t][2]);
            acc[t][3] = dot2(s0, m0.w, acc[t][3]);
            acc[t][0] = dot2(s1, m1.x, acc[t][0]);
            acc[t][1] = dot2(s1, m1.y, acc[t][1]);
            acc[t][2] = dot2(s1, m1.z, acc[t][2]);
            acc[t][3] = dot2(s1, m1.w, acc[t][3]);
            acc[t][0] = dot2(s2, m2.x, acc[t][0]);
            acc[t][1] = dot2(s2, m2.y, acc[t][1]);
            acc[t][2] = dot2(s2, m2.z, acc[t][2]);
            acc[t][3] = dot2(s2, m2.w, acc[t][3]);
            acc[t][0] = dot2(s3, m3.x, acc[t][0]);
            acc[t][1] = dot2(s3, m3.y, acc[t][1]);
            acc[t][2] = dot2(s3, m3.z, acc[t][2]);
            acc[t][3] = dot2(s3, m3.w, acc[t][3]);
        }
    }

    // ---- per-wave restage + NT coalesced splat stores (16 KiB/token) ----
    float* ost = ostage + w * RANK;
    #pragma unroll
    for (int t = 0; t < TB; ++t) {
        ((float4*)ost)[l] =
            make_float4(acc[t][0], acc[t][1], acc[t][2], acc[t][3]);
        f4v* orow = (f4v*)(out + (tok0 + t) * HIDDEN);
        #pragma unroll
        for (int s = 0; s < 16; ++s) {
            const float v = ost[(s << 4) + (l >> 2)];  // 4-lane bcast, free
            const f4v sp = {v, v, v, v};
            __builtin_nontemporal_store(sp, orow + (s << 6) + l);
        }
    }
}

extern "C" void kernel_launch(void* const* d_in, const int* in_sizes, int n_in,
                              void* d_out, int out_size, void* d_ws, size_t ws_size,
                              hipStream_t stream) {
    const float* x = (const float*)d_in[0];
    const float* M = (const float*)d_in[1];
    float* out     = (float*)d_out;

    unsigned int* Mp = (unsigned int*)d_ws;    // 128 KiB packed M

    const int T = in_sizes[0] / HIDDEN;        // 16384 tokens
    const int smem_bytes = 147456;             // 128 KiB M + 16 KiB ostage

    (void)hipFuncSetAttribute((const void*)mora_fused,
                              hipFuncAttributeMaxDynamicSharedMemorySize,
                              smem_bytes);

    hipLaunchKernelGGL(mora_pack, dim3(128), dim3(256), 0, stream, M, Mp);
    hipLaunchKernelGGL(mora_fused, dim3(T / (16 * TB)), dim3(NTH), smem_bytes,
                       stream, x, Mp, out);
}

// Round 18
// 86.785 us; speedup vs baseline: 1.1556x; 1.0389x over previous
//
#include <hip/hip_runtime.h>

#define HIDDEN 4096
#define RANK   256
#define G      16
#define NTH    1024   // 16 waves, 1 block/CU (LDS-forced)
#define TB     4      // tokens per wave (16 waves * 4 = 64 tokens/block)

typedef _Float16 h2d __attribute__((ext_vector_type(2)));
typedef float    f4v __attribute__((ext_vector_type(4)));

__device__ __forceinline__ unsigned int pkf16(float a, float b) {
    auto h = __builtin_amdgcn_cvt_pkrtz(a, b);
    return __builtin_bit_cast(unsigned int, h);
}
__device__ __forceinline__ float dot2(unsigned int a, unsigned int b, float c) {
    return __builtin_amdgcn_fdot2(__builtin_bit_cast(h2d, a),
                                  __builtin_bit_cast(h2d, b), c, false);
}
__device__ __forceinline__ float4 f4add(float4 a, float4 b) {
    return make_float4(a.x + b.x, a.y + b.y, a.z + b.z, a.w + b.w);
}

// ---------------------------------------------------------------------------
// Single launch. Each block packs M (f32, global) -> f16 row-pairs in LDS
// itself (256 KB from L2/L3 per block, 16 float4 loads + 8 ds_write_b128
// per thread), then a cheap barrier (drains only the pack), then R17's
// drifting-wave pipeline: compress 4 tokens in registers -> readlane->dot2
// expand against LDS M -> per-wave restage -> NT coalesced splat stores.
// x-loads deliberately AFTER the barrier so waves desynchronize and mix
// HBM read/write directions (R17's proven win).
// Dynamic LDS: [0,131072) M f16-pairs; [131072,147456) ostage f32[16][256].
// ---------------------------------------------------------------------------
__global__ __launch_bounds__(NTH)
void mora_fused(const float* __restrict__ x,    // [T, HIDDEN]
                const float* __restrict__ Mg,   // [RANK, RANK] f32
                float* __restrict__ out)        // [T, HIDDEN]
{
    extern __shared__ unsigned char smem[];
    unsigned int* Ml = (unsigned int*)smem;            // [128][256] f16 pairs
    float* ostage    = (float*)(smem + 131072);        // [16][256]

    const int  tid  = threadIdx.x;
    const int  w    = tid >> 6;    // wave 0..15
    const int  l    = tid & 63;
    const long tok0 = (long)blockIdx.x * (16 * TB) + (long)w * TB;

    // ---- self-pack M -> LDS: Ml[pr*256+k] = {f16 M[2pr][k], f16 M[2pr+1][k]}
    {
        const float4* Mg4 = (const float4*)Mg;     // row = 64 float4
        uint4* Ml4w = (uint4*)Ml;
        #pragma unroll
        for (int i = 0; i < 8; ++i) {
            const int idx4 = tid + (i << 10);      // 0..8191 (uint4 units)
            const int pr   = idx4 >> 6;            // pair-row 0..127
            const int c4   = idx4 & 63;            // float4-col
            const float4 a = Mg4[(2 * pr)     * 64 + c4];
            const float4 b = Mg4[(2 * pr + 1) * 64 + c4];
            uint4 p;
            p.x = pkf16(a.x, b.x);
            p.y = pkf16(a.y, b.y);
            p.z = pkf16(a.z, b.z);
            p.w = pkf16(a.w, b.w);
            Ml4w[idx4] = p;
        }
    }
    __syncthreads();   // drains only the pack (256 KB from L2/L3 — cheap)

    // ---- compress (registers only): lane owns rows 4l..4l+3 ----
    unsigned int cp0[TB], cp1[TB];
    #pragma unroll
    for (int t = 0; t < TB; ++t) {
        const float4* xr = (const float4*)(x + (tok0 + t) * HIDDEN) + l;
        float4 e = xr[0];
        float4 o = xr[64];
        #pragma unroll
        for (int gi = 1; gi < G / 2; ++gi) {
            e = f4add(e, xr[(2 * gi) * 64]);
            o = f4add(o, xr[(2 * gi + 1) * 64]);
        }
        e = f4add(e, o);
        cp0[t] = pkf16(e.x, e.y);
        cp1[t] = pkf16(e.z, e.w);
    }

    // ---- expand: acc[t][c] = sum_r comp[t][r] * M[r][4l+c] ----
    float acc[TB][4];
    #pragma unroll
    for (int t = 0; t < TB; ++t) {
        acc[t][0] = 0.f; acc[t][1] = 0.f; acc[t][2] = 0.f; acc[t][3] = 0.f;
    }

    const uint4* Ml4 = (const uint4*)Ml + l;   // pair-row stride = 64 uint4
    #pragma unroll 2
    for (int i = 0; i < 32; ++i) {
        const uint4 m0 = Ml4[(4 * i + 0) << 6];   // 1 KiB b128, conflict-free
        const uint4 m1 = Ml4[(4 * i + 1) << 6];
        const uint4 m2 = Ml4[(4 * i + 2) << 6];
        const uint4 m3 = Ml4[(4 * i + 3) << 6];
        #pragma unroll
        for (int t = 0; t < TB; ++t) {
            const unsigned s0 = (unsigned)__builtin_amdgcn_readlane((int)cp0[t], 2 * i);
            const unsigned s1 = (unsigned)__builtin_amdgcn_readlane((int)cp1[t], 2 * i);
            const unsigned s2 = (unsigned)__builtin_amdgcn_readlane((int)cp0[t], 2 * i + 1);
            const unsigned s3 = (unsigned)__builtin_amdgcn_readlane((int)cp1[t], 2 * i + 1);
            acc[t][0] = dot2(s0, m0.x, acc[t][0]);
            acc[t][1] = dot2(s0, m0.y, acc[t][1]);
            acc[t][2] = dot2(s0, m0.z, acc[t][2]);
            acc[t][3] = dot2(s0, m0.w, acc[t][3]);
            acc[t][0] = dot2(s1, m1.x, acc[t][0]);
            acc[t][1] = dot2(s1, m1.y, acc[t][1]);
            acc[t][2] = dot2(s1, m1.z, acc[t][2]);
            acc[t][3] = dot2(s1, m1.w, acc[t][3]);
            acc[t][0] = dot2(s2, m2.x, acc[t][0]);
            acc[t][1] = dot2(s2, m2.y, acc[t][1]);
            acc[t][2] = dot2(s2, m2.z, acc[t][2]);
            acc[t][3] = dot2(s2, m2.w, acc[t][3]);
            acc[t][0] = dot2(s3, m3.x, acc[t][0]);
            acc[t][1] = dot2(s3, m3.y, acc[t][1]);
            acc[t][2] = dot2(s3, m3.z, acc[t][2]);
            acc[t][3] = dot2(s3, m3.w, acc[t][3]);
        }
    }

    // ---- per-wave restage + NT coalesced splat stores (16 KiB/token) ----
    float* ost = ostage + w * RANK;
    #pragma unroll
    for (int t = 0; t < TB; ++t) {
        ((float4*)ost)[l] =
            make_float4(acc[t][0], acc[t][1], acc[t][2], acc[t][3]);
        f4v* orow = (f4v*)(out + (tok0 + t) * HIDDEN);
        #pragma unroll
        for (int s = 0; s < 16; ++s) {
            const float v = ost[(s << 4) + (l >> 2)];  // 4-lane bcast, free
            const f4v sp = {v, v, v, v};
            __builtin_nontemporal_store(sp, orow + (s << 6) + l);
        }
    }
}

extern "C" void kernel_launch(void* const* d_in, const int* in_sizes, int n_in,
                              void* d_out, int out_size, void* d_ws, size_t ws_size,
                              hipStream_t stream) {
    const float* x = (const float*)d_in[0];
    const float* M = (const float*)d_in[1];
    float* out     = (float*)d_out;

    const int T = in_sizes[0] / HIDDEN;        // 16384 tokens
    const int smem_bytes = 147456;             // 128 KiB M + 16 KiB ostage

    (void)hipFuncSetAttribute((const void*)mora_fused,
                              hipFuncAttributeMaxDynamicSharedMemorySize,
                              smem_bytes);

    hipLaunchKernelGGL(mora_fused, dim3(T / (16 * TB)), dim3(NTH), smem_bytes,
                       stream, x, M, out);
}